// Round 1
// baseline (683.302 us; speedup 1.0000x reference)
//
#include <hip/hip_runtime.h>
#include <cstdint>
#include <cstddef>

typedef __bf16 bf16x8 __attribute__((ext_vector_type(8)));
typedef float f32x4 __attribute__((ext_vector_type(4)));
typedef unsigned short u16;
typedef unsigned short u16x8 __attribute__((ext_vector_type(8)));

#define ROWS 32768       // B*T*S
#define DMODEL 1024
#define NQKV 1536        // H*HD + 2*KVH*HD
#define SCALE_ 0.125f    // HD^-0.5
#define CAP_ 50.0f

__device__ __forceinline__ u16 f2bf(float f) {
    unsigned u = __float_as_uint(f);
    u += 0x7fffu + ((u >> 16) & 1u);   // RNE
    return (u16)(u >> 16);
}
__device__ __forceinline__ float bf2f(u16 b) {
    return __uint_as_float(((unsigned)b) << 16);
}

// ---------------- elementwise f32 -> bf16 (x) ----------------
__global__ __launch_bounds__(256) void f32_to_bf16_vec(
    const float* __restrict__ in, u16* __restrict__ out, int n4)
{
    int i = blockIdx.x * 256 + threadIdx.x;
    if (i >= n4) return;
    float4 f = ((const float4*)in)[i];
    ushort4 u;
    u.x = f2bf(f.x); u.y = f2bf(f.y); u.z = f2bf(f.z); u.w = f2bf(f.w);
    ((ushort4*)out)[i] = u;
}

// ---------------- transpose f32 [R][C] -> bf16 [C][R] ----------------
__global__ __launch_bounds__(256) void transpose_bf16(
    const float* __restrict__ src, u16* __restrict__ dst, int R, int C)
{
    __shared__ float tile[32][33];
    int c0 = blockIdx.x * 32;
    int r0 = blockIdx.y * 32;
    int tx = threadIdx.x & 31;
    int ty = threadIdx.x >> 5;        // 0..7
#pragma unroll
    for (int i = 0; i < 32; i += 8)
        tile[ty + i][tx] = src[(size_t)(r0 + ty + i) * C + (c0 + tx)];
    __syncthreads();
#pragma unroll
    for (int i = 0; i < 32; i += 8)
        dst[(size_t)(c0 + ty + i) * R + (r0 + tx)] = f2bf(tile[tx][ty + i]);
}

// ---------------- MFMA GEMM: A[M][K] bf16 @ Bt[N][K] bf16 -> C[M][N] ----------------
// 128x128 tile, BK=32, 4 waves in 2x2, 16x16x32 bf16 mfma.
// A-frag: lane holds A[m=lane&15][k=quad*8+j]; B-frag: Bt[n=lane&15][k=quad*8+j];
// C/D: col=lane&15, row=quad*4+reg (learn_hip m89/m92-verified layouts).
template<bool BF16OUT>
__global__ __launch_bounds__(256) void gemm_bt(
    const u16* __restrict__ A, const u16* __restrict__ Bt,
    void* __restrict__ Cout, int M, int N, int K)
{
    __shared__ u16 As[128][32];
    __shared__ u16 Bs[128][32];
    const int tid  = threadIdx.x;
    const int wave = tid >> 6;
    const int lane = tid & 63;
    const int q4   = lane >> 4;
    const int cl   = lane & 15;
    const int wr   = wave >> 1, wc = wave & 1;
    const int m0   = blockIdx.x * 128;
    const int n0   = blockIdx.y * 128;
    const int srow = lane >> 2;          // 0..15
    const int skoff = (lane & 3) * 8;    // elements

    const f32x4 zero = {0.f, 0.f, 0.f, 0.f};
    f32x4 acc[4][4];
#pragma unroll
    for (int i = 0; i < 4; ++i)
#pragma unroll
        for (int j = 0; j < 4; ++j) acc[i][j] = zero;

    for (int k0 = 0; k0 < K; k0 += 32) {
        __syncthreads();
#pragma unroll
        for (int cc = 0; cc < 2; ++cc) {
            int r = 32 * wave + 16 * cc + srow;
            const u16* ga = A + (size_t)(m0 + r) * K + k0 + skoff;
            __builtin_amdgcn_global_load_lds(
                (const __attribute__((address_space(1))) void*)ga,
                (__attribute__((address_space(3))) void*)(&As[32 * wave + 16 * cc][0]),
                16, 0, 0);
            const u16* gb = Bt + (size_t)(n0 + r) * K + k0 + skoff;
            __builtin_amdgcn_global_load_lds(
                (const __attribute__((address_space(1))) void*)gb,
                (__attribute__((address_space(3))) void*)(&Bs[32 * wave + 16 * cc][0]),
                16, 0, 0);
        }
        __syncthreads();
        bf16x8 af[4], bfr[4];
#pragma unroll
        for (int i = 0; i < 4; ++i)
            af[i] = *(const bf16x8*)&As[64 * wr + 16 * i + cl][q4 * 8];
#pragma unroll
        for (int j = 0; j < 4; ++j)
            bfr[j] = *(const bf16x8*)&Bs[64 * wc + 16 * j + cl][q4 * 8];
#pragma unroll
        for (int i = 0; i < 4; ++i)
#pragma unroll
            for (int j = 0; j < 4; ++j)
                acc[i][j] = __builtin_amdgcn_mfma_f32_16x16x32_bf16(
                    af[i], bfr[j], acc[i][j], 0, 0, 0);
    }

#pragma unroll
    for (int i = 0; i < 4; ++i)
#pragma unroll
        for (int j = 0; j < 4; ++j)
#pragma unroll
            for (int r = 0; r < 4; ++r) {
                int row = m0 + 64 * wr + 16 * i + q4 * 4 + r;
                int col = n0 + 64 * wc + 16 * j + cl;
                if (BF16OUT)
                    ((u16*)Cout)[(size_t)row * N + col] = f2bf(acc[i][j][r]);
                else
                    ((float*)Cout)[(size_t)row * N + col] = acc[i][j][r];
            }
}

// ---------------- RMSNorm on q,k head chunks (in place, bf16) ----------------
// 16 lanes per 64-elem chunk, 4 elems/lane. qkv layout [ROWS][1536].
__global__ __launch_bounds__(256) void rmsnorm_qk(
    u16* __restrict__ qkv, const float* __restrict__ qw, const float* __restrict__ kw)
{
    int gid = blockIdx.x * 16 + (threadIdx.x >> 4);   // chunk id
    int l16 = threadIdx.x & 15;
    int row = gid / 20;                               // 16 q + 4 k chunks per row
    int hc  = gid - row * 20;
    const float* w = (hc < 16) ? qw : kw;
    size_t base = (size_t)row * NQKV + hc * 64;
    u16* p = qkv + base + l16 * 4;
    uint2 d = *(const uint2*)p;
    float f0 = bf2f((u16)(d.x & 0xffff));
    float f1 = bf2f((u16)(d.x >> 16));
    float f2 = bf2f((u16)(d.y & 0xffff));
    float f3 = bf2f((u16)(d.y >> 16));
    float ss = f0 * f0 + f1 * f1 + f2 * f2 + f3 * f3;
#pragma unroll
    for (int off = 1; off < 16; off <<= 1) ss += __shfl_xor(ss, off, 64);
    float r = rsqrtf(ss * (1.0f / 64.0f) + 1e-6f);
    float w0 = w[l16 * 4 + 0], w1 = w[l16 * 4 + 1];
    float w2 = w[l16 * 4 + 2], w3 = w[l16 * 4 + 3];
    uint2 o;
    o.x = (unsigned)f2bf(f0 * r * w0) | ((unsigned)f2bf(f1 * r * w1) << 16);
    o.y = (unsigned)f2bf(f2 * r * w2) | ((unsigned)f2bf(f3 * r * w3) << 16);
    *(uint2*)p = o;
}

// ---------------- fused attention, 1 block per (bt, h) ----------------
// 4 waves x 64 Q-rows; online softmax over 4 col-blocks of 64; softcap 50*tanh.
__global__ __launch_bounds__(256, 2) void attention_kernel(
    const u16* __restrict__ qkv, u16* __restrict__ ao)
{
    const int bi  = blockIdx.x;
    const int bt  = bi >> 4;
    const int h   = bi & 15;
    const int kvh = h >> 2;          // GROUPS=4
    const int tid  = threadIdx.x;
    const int wave = tid >> 6;
    const int lane = tid & 63;
    const int q4   = lane >> 4;
    const int cl   = lane & 15;

    __shared__ u16 Vt[64][264];      // V^T, +8 pad (rows stay 16B aligned)
    __shared__ u16 P[4][64][72];     // per-wave P round-trip, +8 pad

    // stage V^T: thread t owns source row s=t (64 bf16)
    {
        const u16* vrow = qkv + (size_t)(bt * 256 + tid) * NQKV + 1280 + kvh * 64;
#pragma unroll
        for (int ch = 0; ch < 8; ++ch) {
            u16x8 v8 = *(const u16x8*)(vrow + ch * 8);
#pragma unroll
            for (int e = 0; e < 8; ++e) Vt[ch * 8 + e][tid] = v8[e];
        }
    }
    __syncthreads();

    const u16* qbase = qkv + (size_t)(bt * 256) * NQKV + h * 64;
    const u16* kbase = qkv + (size_t)(bt * 256) * NQKV + 1024 + kvh * 64;

    const f32x4 zero = {0.f, 0.f, 0.f, 0.f};
    f32x4 o[4][4];
    float m_[4][4], l_[4][4];
#pragma unroll
    for (int i = 0; i < 4; ++i)
#pragma unroll
        for (int r = 0; r < 4; ++r) { m_[i][r] = -1e30f; l_[i][r] = 0.f; }
#pragma unroll
    for (int i = 0; i < 4; ++i)
#pragma unroll
        for (int j = 0; j < 4; ++j) o[i][j] = zero;

    for (int nb = 0; nb < 4; ++nb) {
        f32x4 s[4][4];
#pragma unroll
        for (int i = 0; i < 4; ++i)
#pragma unroll
            for (int j = 0; j < 4; ++j) s[i][j] = zero;

        // S = Q @ K^T (contraction over HD=64, two k-steps of 32)
#pragma unroll
        for (int ks = 0; ks < 2; ++ks) {
            bf16x8 qa[4], kb[4];
#pragma unroll
            for (int i = 0; i < 4; ++i)
                qa[i] = *(const bf16x8*)(qbase +
                    (size_t)(wave * 64 + 16 * i + cl) * NQKV + ks * 32 + q4 * 8);
#pragma unroll
            for (int j = 0; j < 4; ++j)
                kb[j] = *(const bf16x8*)(kbase +
                    (size_t)(nb * 64 + 16 * j + cl) * NQKV + ks * 32 + q4 * 8);
#pragma unroll
            for (int i = 0; i < 4; ++i)
#pragma unroll
                for (int j = 0; j < 4; ++j)
                    s[i][j] = __builtin_amdgcn_mfma_f32_16x16x32_bf16(
                        qa[i], kb[j], s[i][j], 0, 0, 0);
        }

        // softcap: z = s*SCALE; capped = CAP * tanh(z/CAP) (overflow-safe form)
        float bm[4][4];
#pragma unroll
        for (int i = 0; i < 4; ++i)
#pragma unroll
            for (int r = 0; r < 4; ++r) bm[i][r] = -1e30f;
#pragma unroll
        for (int i = 0; i < 4; ++i)
#pragma unroll
            for (int j = 0; j < 4; ++j)
#pragma unroll
                for (int r = 0; r < 4; ++r) {
                    float y = s[i][j][r] * (SCALE_ / CAP_);
                    float e = __expf(2.0f * y);
                    float capped = CAP_ * (1.0f - 2.0f / (e + 1.0f));
                    s[i][j][r] = capped;
                    bm[i][r] = fmaxf(bm[i][r], capped);
                }
#pragma unroll
        for (int off = 1; off < 16; off <<= 1)
#pragma unroll
            for (int i = 0; i < 4; ++i)
#pragma unroll
                for (int r = 0; r < 4; ++r)
                    bm[i][r] = fmaxf(bm[i][r], __shfl_xor(bm[i][r], off, 64));

        float alpha[4][4];
#pragma unroll
        for (int i = 0; i < 4; ++i)
#pragma unroll
            for (int r = 0; r < 4; ++r) {
                float mn = fmaxf(m_[i][r], bm[i][r]);
                alpha[i][r] = __expf(m_[i][r] - mn);
                m_[i][r] = mn;
            }
#pragma unroll
        for (int i = 0; i < 4; ++i)
#pragma unroll
            for (int j = 0; j < 4; ++j)
#pragma unroll
                for (int r = 0; r < 4; ++r) o[i][j][r] *= alpha[i][r];

        float rs[4][4];
#pragma unroll
        for (int i = 0; i < 4; ++i)
#pragma unroll
            for (int r = 0; r < 4; ++r) rs[i][r] = 0.f;
#pragma unroll
        for (int i = 0; i < 4; ++i)
#pragma unroll
            for (int j = 0; j < 4; ++j)
#pragma unroll
                for (int r = 0; r < 4; ++r) {
                    float p = __expf(s[i][j][r] - m_[i][r]);
                    s[i][j][r] = p;
                    rs[i][r] += p;
                }
#pragma unroll
        for (int off = 1; off < 16; off <<= 1)
#pragma unroll
            for (int i = 0; i < 4; ++i)
#pragma unroll
                for (int r = 0; r < 4; ++r) rs[i][r] += __shfl_xor(rs[i][r], off, 64);
#pragma unroll
        for (int i = 0; i < 4; ++i)
#pragma unroll
            for (int r = 0; r < 4; ++r) l_[i][r] = l_[i][r] * alpha[i][r] + rs[i][r];

        // P (C-layout) -> LDS -> A-layout
#pragma unroll
        for (int i = 0; i < 4; ++i)
#pragma unroll
            for (int j = 0; j < 4; ++j)
#pragma unroll
                for (int r = 0; r < 4; ++r)
                    P[wave][16 * i + q4 * 4 + r][16 * j + cl] = f2bf(s[i][j][r]);
        __syncthreads();   // uniform trip count; also drains LDS writes

        // O += P @ V  (contraction over this 64-col block, two k-steps of 32)
#pragma unroll
        for (int ks = 0; ks < 2; ++ks) {
            bf16x8 pa[4], vb[4];
#pragma unroll
            for (int i = 0; i < 4; ++i)
                pa[i] = *(const bf16x8*)&P[wave][16 * i + cl][ks * 32 + q4 * 8];
#pragma unroll
            for (int j = 0; j < 4; ++j)
                vb[j] = *(const bf16x8*)&Vt[16 * j + cl][nb * 64 + ks * 32 + q4 * 8];
#pragma unroll
            for (int i = 0; i < 4; ++i)
#pragma unroll
                for (int j = 0; j < 4; ++j)
                    o[i][j] = __builtin_amdgcn_mfma_f32_16x16x32_bf16(
                        pa[i], vb[j], o[i][j], 0, 0, 0);
        }
    }

    // normalize + store (bf16) to ao[ROWS][1024], col = h*64 + d
#pragma unroll
    for (int i = 0; i < 4; ++i)
#pragma unroll
        for (int r = 0; r < 4; ++r) {
            float inv = 1.0f / l_[i][r];
            int row = bt * 256 + wave * 64 + 16 * i + q4 * 4 + r;
#pragma unroll
            for (int j = 0; j < 4; ++j) {
                int col = h * 64 + 16 * j + cl;
                ao[(size_t)row * DMODEL + col] = f2bf(o[i][j][r] * inv);
            }
        }
}

// ---------------- host launch ----------------
extern "C" void kernel_launch(void* const* d_in, const int* in_sizes, int n_in,
                              void* d_out, int out_size, void* d_ws, size_t ws_size,
                              hipStream_t stream)
{
    const float* x  = (const float*)d_in[0];
    const float* Wq = (const float*)d_in[1];
    const float* Wk = (const float*)d_in[2];
    const float* Wv = (const float*)d_in[3];
    const float* Wo = (const float*)d_in[4];
    const float* qw = (const float*)d_in[5];
    const float* kw = (const float*)d_in[6];
    float* out = (float*)d_out;

    char* ws = (char*)d_ws;
    u16* Xb  = (u16*)(ws);                            // 32768x1024 bf16 (64 MB)
    u16* QKV = (u16*)(ws + (size_t)67108864);         // 32768x1536 bf16 (96 MB)
    u16* AO  = (u16*)(ws + (size_t)167772160);        // 32768x1024 bf16 (64 MB)
    u16* WcT = (u16*)(ws + (size_t)234881024);        // 1536x1024 bf16  (3 MB)
    u16* WoT = (u16*)(ws + (size_t)238026752);        // 1024x1024 bf16  (2 MB)

    // x -> bf16
    f32_to_bf16_vec<<<dim3(32768), dim3(256), 0, stream>>>(x, Xb, 8388608);
    // W^T (concatenated q|k|v) and Wo^T, bf16
    transpose_bf16<<<dim3(32, 32), dim3(256), 0, stream>>>(Wq, WcT, 1024, 1024);
    transpose_bf16<<<dim3(8, 32), dim3(256), 0, stream>>>(Wk, WcT + (size_t)1024 * 1024, 1024, 256);
    transpose_bf16<<<dim3(8, 32), dim3(256), 0, stream>>>(Wv, WcT + (size_t)1280 * 1024, 1024, 256);
    transpose_bf16<<<dim3(32, 32), dim3(256), 0, stream>>>(Wo, WoT, 1024, 1024);
    // QKV projection
    gemm_bt<true><<<dim3(256, 12), dim3(256), 0, stream>>>(Xb, WcT, (void*)QKV, ROWS, NQKV, 1024);
    // RMSNorm q,k
    rmsnorm_qk<<<dim3(40960), dim3(256), 0, stream>>>(QKV, qw, kw);
    // attention
    attention_kernel<<<dim3(2048), dim3(256), 0, stream>>>(QKV, AO);
    // output projection -> fp32 d_out
    gemm_bt<false><<<dim3(256, 8), dim3(256), 0, stream>>>(AO, WoT, (void*)out, ROWS, DMODEL, 1024);
}

// Round 2
// 660.082 us; speedup vs baseline: 1.0352x; 1.0352x over previous
//
#include <hip/hip_runtime.h>
#include <cstdint>
#include <cstddef>

typedef __bf16 bf16x8 __attribute__((ext_vector_type(8)));
typedef float f32x4 __attribute__((ext_vector_type(4)));
typedef unsigned short u16;
typedef unsigned int u32;
typedef unsigned short u16x8 __attribute__((ext_vector_type(8)));

#define ROWS 32768       // B*T*S
#define DMODEL 1024
#define NQKV 1536        // H*HD + 2*KVH*HD
// folded softcap constants: logits z = dot*rq*rk*0.125, capped = 50*tanh(z/50)
//   e2 = exp2(dot*rq*rk * C1),  C1 = 2*0.125/50*log2(e)
//   p  = exp2(B2 - A2 * rcp(e2+1)),  A2 = 100*log2(e), B2 = 50*log2(e)
#define C1_ 0.0072134752044448170f
#define A2_ 144.26950408889634f
#define B2_ 72.13475204444817f

__device__ __forceinline__ u16 f2bf(float f) {
    unsigned u = __float_as_uint(f);
    u += 0x7fffu + ((u >> 16) & 1u);   // RNE
    return (u16)(u >> 16);
}
__device__ __forceinline__ float bf_lo(u32 u) { return __uint_as_float(u << 16); }
__device__ __forceinline__ float bf_hi(u32 u) { return __uint_as_float(u & 0xffff0000u); }
__device__ __forceinline__ u32 pack_rne(float lo, float hi) {
    return (u32)f2bf(lo) | ((u32)f2bf(hi) << 16);
}

// ---------------- elementwise f32 -> bf16 (x) ----------------
__global__ __launch_bounds__(256) void f32_to_bf16_vec(
    const float* __restrict__ in, u16* __restrict__ out, int n4)
{
    int i = blockIdx.x * 256 + threadIdx.x;
    if (i >= n4) return;
    float4 f = ((const float4*)in)[i];
    ushort4 u;
    u.x = f2bf(f.x); u.y = f2bf(f.y); u.z = f2bf(f.z); u.w = f2bf(f.w);
    ((ushort4*)out)[i] = u;
}

// ---------------- transpose f32 [R][C] -> bf16 [C][R] ----------------
__global__ __launch_bounds__(256) void transpose_bf16(
    const float* __restrict__ src, u16* __restrict__ dst, int R, int C)
{
    __shared__ float tile[32][33];
    int c0 = blockIdx.x * 32;
    int r0 = blockIdx.y * 32;
    int tx = threadIdx.x & 31;
    int ty = threadIdx.x >> 5;        // 0..7
#pragma unroll
    for (int i = 0; i < 32; i += 8)
        tile[ty + i][tx] = src[(size_t)(r0 + ty + i) * C + (c0 + tx)];
    __syncthreads();
#pragma unroll
    for (int i = 0; i < 32; i += 8)
        dst[(size_t)(c0 + ty + i) * R + (r0 + tx)] = f2bf(tile[tx][ty + i]);
}

// ---------------- MFMA GEMM: A[M][K] bf16 @ Bt[N][K] bf16 -> C[M][N] ----------------
template<bool BF16OUT>
__global__ __launch_bounds__(256) void gemm_bt(
    const u16* __restrict__ A, const u16* __restrict__ Bt,
    void* __restrict__ Cout, int M, int N, int K)
{
    __shared__ u16 As[128][32];
    __shared__ u16 Bs[128][32];
    const int tid  = threadIdx.x;
    const int wave = tid >> 6;
    const int lane = tid & 63;
    const int q4   = lane >> 4;
    const int cl   = lane & 15;
    const int wr   = wave >> 1, wc = wave & 1;
    const int m0   = blockIdx.x * 128;
    const int n0   = blockIdx.y * 128;
    const int srow = lane >> 2;          // 0..15
    const int skoff = (lane & 3) * 8;    // elements

    const f32x4 zero = {0.f, 0.f, 0.f, 0.f};
    f32x4 acc[4][4];
#pragma unroll
    for (int i = 0; i < 4; ++i)
#pragma unroll
        for (int j = 0; j < 4; ++j) acc[i][j] = zero;

    for (int k0 = 0; k0 < K; k0 += 32) {
        __syncthreads();
#pragma unroll
        for (int cc = 0; cc < 2; ++cc) {
            int r = 32 * wave + 16 * cc + srow;
            const u16* ga = A + (size_t)(m0 + r) * K + k0 + skoff;
            __builtin_amdgcn_global_load_lds(
                (const __attribute__((address_space(1))) void*)ga,
                (__attribute__((address_space(3))) void*)(&As[32 * wave + 16 * cc][0]),
                16, 0, 0);
            const u16* gb = Bt + (size_t)(n0 + r) * K + k0 + skoff;
            __builtin_amdgcn_global_load_lds(
                (const __attribute__((address_space(1))) void*)gb,
                (__attribute__((address_space(3))) void*)(&Bs[32 * wave + 16 * cc][0]),
                16, 0, 0);
        }
        __syncthreads();
        bf16x8 af[4], bfr[4];
#pragma unroll
        for (int i = 0; i < 4; ++i)
            af[i] = *(const bf16x8*)&As[64 * wr + 16 * i + cl][q4 * 8];
#pragma unroll
        for (int j = 0; j < 4; ++j)
            bfr[j] = *(const bf16x8*)&Bs[64 * wc + 16 * j + cl][q4 * 8];
#pragma unroll
        for (int i = 0; i < 4; ++i)
#pragma unroll
            for (int j = 0; j < 4; ++j)
                acc[i][j] = __builtin_amdgcn_mfma_f32_16x16x32_bf16(
                    af[i], bfr[j], acc[i][j], 0, 0, 0);
    }

#pragma unroll
    for (int i = 0; i < 4; ++i)
#pragma unroll
        for (int j = 0; j < 4; ++j)
#pragma unroll
            for (int r = 0; r < 4; ++r) {
                int row = m0 + 64 * wr + 16 * i + q4 * 4 + r;
                int col = n0 + 64 * wc + 16 * j + cl;
                if (BF16OUT)
                    ((u16*)Cout)[(size_t)row * N + col] = f2bf(acc[i][j][r]);
                else
                    ((float*)Cout)[(size_t)row * N + col] = acc[i][j][r];
            }
}

// ---------------- fused attention, 1 block per (bt, h) ----------------
// 4 waves x 64 Q-rows. Fixed-max softmax (softcap bounds logits), l via
// mfma-with-ones, QK rmsnorm fused (scalars folded into the exponent),
// half-width per-wave P round-trip, no in-loop barriers.
__global__ __launch_bounds__(256, 3) void attention_kernel(
    const u16* __restrict__ qkv, const float* __restrict__ qw,
    const float* __restrict__ kw, u16* __restrict__ ao)
{
    const int bi  = blockIdx.x;
    const int bt  = bi >> 4;
    const int h   = bi & 15;
    const int kvh = h >> 2;          // GROUPS=4
    const int tid  = threadIdx.x;
    const int wave = tid >> 6;
    const int lane = tid & 63;
    const int q4   = lane >> 4;
    const int cl   = lane & 15;

    __shared__ __align__(16) u16 Vt[64][264];   // V^T, pad keeps 528B rows (16B aligned)
    __shared__ __align__(16) u16 P[4][64][40];  // per-wave half-width P (32 cols + pad), 80B rows

    // stage V^T: thread t owns source row s=t (64 bf16)
    {
        const u16* vrow = qkv + (size_t)(bt * 256 + tid) * NQKV + 1280 + kvh * 64;
#pragma unroll
        for (int ch = 0; ch < 8; ++ch) {
            u16x8 v8 = *(const u16x8*)(vrow + ch * 8);
#pragma unroll
            for (int e = 0; e < 8; ++e) Vt[ch * 8 + e][tid] = v8[e];
        }
    }
    __syncthreads();

    const u16* qbase = qkv + (size_t)(bt * 256) * NQKV + h * 64;
    const u16* kbase = qkv + (size_t)(bt * 256) * NQKV + 1024 + kvh * 64;

    // ---- hoist Q fragments: load, rms, scale by wq*wk (RNE repack) ----
    uint4 qa[2][4];          // [ks][i], each = bf16x8
    float rq[4];
    float wqk[2][8];
#pragma unroll
    for (int ks = 0; ks < 2; ++ks)
#pragma unroll
        for (int e = 0; e < 8; ++e) {
            int d = ks * 32 + q4 * 8 + e;
            wqk[ks][e] = qw[d] * kw[d];
        }
#pragma unroll
    for (int i = 0; i < 4; ++i) {
#pragma unroll
        for (int ks = 0; ks < 2; ++ks)
            qa[ks][i] = *(const uint4*)(qbase +
                (size_t)(wave * 64 + 16 * i + cl) * NQKV + ks * 32 + q4 * 8);
        float ss = 0.f;
#pragma unroll
        for (int ks = 0; ks < 2; ++ks) {
            const u32* u = (const u32*)&qa[ks][i];
#pragma unroll
            for (int e = 0; e < 4; ++e) {
                float lo = bf_lo(u[e]), hi = bf_hi(u[e]);
                ss += lo * lo + hi * hi;
            }
        }
        ss += __shfl_xor(ss, 16, 64);
        ss += __shfl_xor(ss, 32, 64);
        rq[i] = rsqrtf(ss * (1.0f / 64.0f) + 1e-6f);
        // apply wq*wk element-wise (exact when w==1: repack of unchanged bf16)
#pragma unroll
        for (int ks = 0; ks < 2; ++ks) {
            u32* u = (u32*)&qa[ks][i];
#pragma unroll
            for (int e = 0; e < 4; ++e) {
                float lo = bf_lo(u[e]) * wqk[ks][2 * e];
                float hi = bf_hi(u[e]) * wqk[ks][2 * e + 1];
                u[e] = pack_rne(lo, hi);
            }
        }
    }
    // redistribute rq from A-layout lanes (row=cl) to C-layout rows (16i+4*q4+r)
    float rqc[4][4];
#pragma unroll
    for (int i = 0; i < 4; ++i)
#pragma unroll
        for (int r = 0; r < 4; ++r)
            rqc[i][r] = __shfl(rq[i], 4 * q4 + r, 64);

    const f32x4 zero = {0.f, 0.f, 0.f, 0.f};
    f32x4 o[4][4];
    f32x4 lacc[4];
#pragma unroll
    for (int i = 0; i < 4; ++i) {
        lacc[i] = zero;
#pragma unroll
        for (int j = 0; j < 4; ++j) o[i][j] = zero;
    }
    bf16x8 ones;
#pragma unroll
    for (int e = 0; e < 8; ++e) ones[e] = (__bf16)1.0f;

    for (int nb = 0; nb < 4; ++nb) {
#pragma unroll
        for (int jh = 0; jh < 2; ++jh) {       // K-col halves of 32
#pragma unroll
            for (int jj = 0; jj < 2; ++jj) {
                const int j = 2 * jh + jj;
                uint4 kb[2];
#pragma unroll
                for (int ks = 0; ks < 2; ++ks)
                    kb[ks] = *(const uint4*)(kbase +
                        (size_t)(nb * 64 + 16 * j + cl) * NQKV + ks * 32 + q4 * 8);
                float ss = 0.f;
#pragma unroll
                for (int ks = 0; ks < 2; ++ks) {
                    const u32* u = (const u32*)&kb[ks];
#pragma unroll
                    for (int e = 0; e < 4; ++e) {
                        float lo = bf_lo(u[e]), hi = bf_hi(u[e]);
                        ss += lo * lo + hi * hi;
                    }
                }
                ss += __shfl_xor(ss, 16, 64);
                ss += __shfl_xor(ss, 32, 64);
                float rkc1 = rsqrtf(ss * (1.0f / 64.0f) + 1e-6f) * C1_;

#pragma unroll
                for (int i = 0; i < 4; ++i) {
                    f32x4 s = __builtin_amdgcn_mfma_f32_16x16x32_bf16(
                        *(const bf16x8*)&qa[0][i], *(const bf16x8*)&kb[0], zero, 0, 0, 0);
                    s = __builtin_amdgcn_mfma_f32_16x16x32_bf16(
                        *(const bf16x8*)&qa[1][i], *(const bf16x8*)&kb[1], s, 0, 0, 0);
#pragma unroll
                    for (int r = 0; r < 4; ++r) {
                        float e2 = __builtin_amdgcn_exp2f(s[r] * rqc[i][r] * rkc1);
                        float rc = __builtin_amdgcn_rcpf(e2 + 1.0f);
                        float p  = __builtin_amdgcn_exp2f(fmaf(-A2_, rc, B2_));
                        P[wave][16 * i + q4 * 4 + r][16 * jj + cl] = f2bf(p);
                    }
                }
            }
            // PV for this 32-wide k-chunk (per-wave LDS: DS in-order, no barrier)
            bf16x8 vb[4];
#pragma unroll
            for (int j2 = 0; j2 < 4; ++j2)
                vb[j2] = *(const bf16x8*)&Vt[16 * j2 + cl][nb * 64 + jh * 32 + q4 * 8];
#pragma unroll
            for (int i = 0; i < 4; ++i) {
                bf16x8 pa = *(const bf16x8*)&P[wave][16 * i + cl][q4 * 8];
#pragma unroll
                for (int j2 = 0; j2 < 4; ++j2)
                    o[i][j2] = __builtin_amdgcn_mfma_f32_16x16x32_bf16(
                        pa, vb[j2], o[i][j2], 0, 0, 0);
                lacc[i] = __builtin_amdgcn_mfma_f32_16x16x32_bf16(
                    pa, ones, lacc[i], 0, 0, 0);
            }
        }
    }

    // normalize + store (bf16) to ao[ROWS][1024], col = h*64 + d
#pragma unroll
    for (int i = 0; i < 4; ++i)
#pragma unroll
        for (int r = 0; r < 4; ++r) {
            float inv = 1.0f / lacc[i][r];
            int row = bt * 256 + wave * 64 + 16 * i + q4 * 4 + r;
#pragma unroll
            for (int j = 0; j < 4; ++j) {
                int col = h * 64 + 16 * j + cl;
                ao[(size_t)row * DMODEL + col] = f2bf(o[i][j][r] * inv);
            }
        }
}

// ---------------- host launch ----------------
extern "C" void kernel_launch(void* const* d_in, const int* in_sizes, int n_in,
                              void* d_out, int out_size, void* d_ws, size_t ws_size,
                              hipStream_t stream)
{
    const float* x  = (const float*)d_in[0];
    const float* Wq = (const float*)d_in[1];
    const float* Wk = (const float*)d_in[2];
    const float* Wv = (const float*)d_in[3];
    const float* Wo = (const float*)d_in[4];
    const float* qw = (const float*)d_in[5];
    const float* kw = (const float*)d_in[6];
    float* out = (float*)d_out;

    char* ws = (char*)d_ws;
    u16* Xb  = (u16*)(ws);                            // 32768x1024 bf16 (64 MB)
    u16* QKV = (u16*)(ws + (size_t)67108864);         // 32768x1536 bf16 (96 MB)
    u16* AO  = (u16*)(ws + (size_t)167772160);        // 32768x1024 bf16 (64 MB)
    u16* WcT = (u16*)(ws + (size_t)234881024);        // 1536x1024 bf16  (3 MB)
    u16* WoT = (u16*)(ws + (size_t)238026752);        // 1024x1024 bf16  (2 MB)

    // x -> bf16
    f32_to_bf16_vec<<<dim3(32768), dim3(256), 0, stream>>>(x, Xb, 8388608);
    // W^T (concatenated q|k|v) and Wo^T, bf16
    transpose_bf16<<<dim3(32, 32), dim3(256), 0, stream>>>(Wq, WcT, 1024, 1024);
    transpose_bf16<<<dim3(8, 32), dim3(256), 0, stream>>>(Wk, WcT + (size_t)1024 * 1024, 1024, 256);
    transpose_bf16<<<dim3(8, 32), dim3(256), 0, stream>>>(Wv, WcT + (size_t)1280 * 1024, 1024, 256);
    transpose_bf16<<<dim3(32, 32), dim3(256), 0, stream>>>(Wo, WoT, 1024, 1024);
    // QKV projection (q,k unnormalized; attention fuses rmsnorm)
    gemm_bt<true><<<dim3(256, 12), dim3(256), 0, stream>>>(Xb, WcT, (void*)QKV, ROWS, NQKV, 1024);
    // attention
    attention_kernel<<<dim3(2048), dim3(256), 0, stream>>>(QKV, qw, kw, AO);
    // output projection -> fp32 d_out
    gemm_bt<false><<<dim3(256, 8), dim3(256), 0, stream>>>(AO, WoT, (void*)out, ROWS, DMODEL, 1024);
}